// Round 7
// baseline (236.826 us; speedup 1.0000x reference)
//
#include <hip/hip_runtime.h>

// ScRRAMBLe capsule layer — R10: split kernels, coalesced Ci tiling.
//   A) xr_part[ch,c,k,m] = sum_{ij in ch} Ci[ij,c,k] * x[ij,m]
//   B) y[c,j,l] = sum_{k,m} Wi[c,j,k,l,m] * (sum_ch xr_part[ch,c,k,m])
//
// R9 post-mortem: GLDS conveyor REGRESSED (89us, VALUBusy 5.9%) — compiler
// inserts vmcnt(0) before ds_reads that depend on global_load_lds, draining
// the pipeline every tile. Cross-round accounting (R1 split: route+transform
// ~77us; fused variants 80-98us regardless of transform impl) pins the hog
// on the Ci COLUMN GATHER: stride-8KB, 1 line/lane, 25% line use, 4x
// redundant across blocks, cold HBM. R10: block = (16 capsules x 128 ij);
// Ci tile staged COALESCED (256B/ij segments, every line used once
// chip-wide), x tile linear; inner loop pure LDS broadcast + FMA.
// Route predicted ~7us (was ~50). Transform = R1's best-measured structure.
// Predicted total ~185-200us (vs 232.6). If ~220: transform is the hog.

typedef float f4 __attribute__((ext_vector_type(4)));

#define NCH 16   // ij chunks of 128; xr partials = 16*512*256 floats = 8 MB

// ---------------- Kernel A: routing, tiled & coalesced ---------------------
// grid (32 capsule-groups, 16 ij-chunks); block 256 (4 waves).
// Stage: Ci tile [128 ij][16 cc] f4 (32KB) + x tile [128 ij][16 mq] f4 (32KB).
// Inner: thread (cc=t>>4, mq=t&15): acc[k](f4 over m) += Ci[ij,cc,k]*x[ij,mq].
__global__ __launch_bounds__(256, 2) void route_kernel(
    const float* __restrict__ x,
    const float* __restrict__ Ci,
    float* __restrict__ xr_part)
{
    const int cg = blockIdx.x;        // 16 capsules: c = cg*16 + cc
    const int ch = blockIdx.y;        // 128 ij:     ij = ch*128 + ijl
    const int t  = threadIdx.x;

    const f4* __restrict__ Ci4 = (const f4*)Ci;   // [2048 ij][512 c]
    const f4* __restrict__ x4  = (const f4*)x;    // [2048 ij][16 mq]

    __shared__ f4 ci_s[2048];   // [ijl][cc]
    __shared__ f4 x_s[2048];    // [ijl][mq]

    #pragma unroll
    for (int u = 0; u < 8; ++u) {
        const int e   = (u << 8) + t;
        const int ijl = e >> 4;
        const int cc  = e & 15;
        // Ci: 256B contiguous per ij row (16 cc x 16B) -> 4x256B segs/instr
        ci_s[e] = Ci4[((ch << 7) + ijl) * 512 + (cg << 4) + cc];
        // x: tile is fully linear 32KB
        x_s[e]  = x4[(ch << 11) + e];
    }
    __syncthreads();

    const int cc = t >> 4;
    const int mq = t & 15;
    f4 a0 = {0.f,0.f,0.f,0.f};
    f4 a1 = {0.f,0.f,0.f,0.f};
    f4 a2 = {0.f,0.f,0.f,0.f};
    f4 a3 = {0.f,0.f,0.f,0.f};
    #pragma unroll 4
    for (int ij = 0; ij < 128; ++ij) {
        const f4 civ = ci_s[(ij << 4) + cc];   // 4 uniq addrs/wave: broadcast
        const f4 xv  = x_s[(ij << 4) + mq];    // 16 uniq addrs: 2-way = free
        a0 += civ.x * xv;
        a1 += civ.y * xv;
        a2 += civ.z * xv;
        a3 += civ.w * xv;
    }

    // xr_part[ch][c][k][mq] (f4): consecutive mq per (c,k) -> 256B segments
    f4* __restrict__ xp4 = (f4*)xr_part;
    const int base = ((ch << 9) + (cg << 4) + cc) << 2;
    xp4[(base + 0) * 16 + mq] = a0;
    xp4[(base + 1) * 16 + mq] = a1;
    xp4[(base + 2) * 16 + mq] = a2;
    xp4[(base + 3) * 16 + mq] = a3;
}

// ---------------- Kernel B: per-capsule transform (R1 lineage) -------------
// grid 2048 = (i*4+j); block 256; wave w owns l in [w*16, w*16+16).
// 16 Wi loads hoisted (64 VGPR, fits 128-cap) + nontemporal; no barriers.
__global__ __launch_bounds__(256, 4) void transform_kernel(
    const float* __restrict__ Wi,
    const float* __restrict__ xr_part,
    float* __restrict__ y)
{
    const int b    = blockIdx.x;
    const int i    = b >> 2;
    const int t    = threadIdx.x;
    const int lane = t & 63;
    const int w    = t >> 6;
    const int lq   = lane >> 4;
    const int m16  = lane & 15;

    // Wi loads first (independent, 1KB/wave-instr), then xr gather under them.
    const f4* __restrict__ W4 = (const f4*)Wi;
    const int wbase = b << 12;          // b * 4096 f4
    const int lw    = w << 4;

    f4 wv[16];
    #pragma unroll
    for (int c2 = 0; c2 < 4; ++c2) {
        const int l = lw + (c2 << 2) + lq;
        #pragma unroll
        for (int k = 0; k < 4; ++k)
            wv[(c2 << 2) + k] =
                __builtin_nontemporal_load(&W4[wbase + (k << 10) + l * 16 + m16]);
    }

    // xr[i,k,m16] = sum over 16 chunk partials (L2/L3-resident).
    const f4* __restrict__ xp4 = (const f4*)xr_part;
    f4 xr0 = {0.f,0.f,0.f,0.f};
    f4 xr1 = {0.f,0.f,0.f,0.f};
    f4 xr2 = {0.f,0.f,0.f,0.f};
    f4 xr3 = {0.f,0.f,0.f,0.f};
    #pragma unroll 4
    for (int ch = 0; ch < NCH; ++ch) {
        const int base = ((ch << 9) + i) << 2;
        xr0 += xp4[(base + 0) * 16 + m16];
        xr1 += xp4[(base + 1) * 16 + m16];
        xr2 += xp4[(base + 2) * 16 + m16];
        xr3 += xp4[(base + 3) * 16 + m16];
    }

    #pragma unroll
    for (int c2 = 0; c2 < 4; ++c2) {
        const int l = lw + (c2 << 2) + lq;
        f4 s = wv[(c2 << 2) + 0] * xr0
             + wv[(c2 << 2) + 1] * xr1
             + wv[(c2 << 2) + 2] * xr2
             + wv[(c2 << 2) + 3] * xr3;
        float p = s.x + s.y + s.z + s.w;
        p += __shfl_xor(p, 1);
        p += __shfl_xor(p, 2);
        p += __shfl_xor(p, 4);
        p += __shfl_xor(p, 8);
        if (m16 == 0) y[(b << 6) + l] = p;
    }
}

extern "C" void kernel_launch(void* const* d_in, const int* in_sizes, int n_in,
                              void* d_out, int out_size, void* d_ws, size_t ws_size,
                              hipStream_t stream) {
    const float* x  = (const float*)d_in[0];   // 131072 floats
    const float* Ci = (const float*)d_in[1];   // 2048*512*4 floats (16 MB)
    const float* Wi = (const float*)d_in[2];   // 512*4*4*64*64 floats (134 MB)
    float* y  = (float*)d_out;                 // 512*4*64 floats
    float* xr = (float*)d_ws;                  // 8 MB partials

    route_kernel<<<dim3(32, NCH), 256, 0, stream>>>(x, Ci, xr);
    transform_kernel<<<2048, 256, 0, stream>>>(Wi, xr, y);
}

// Round 8
// 221.323 us; speedup vs baseline: 1.0701x; 1.0701x over previous
//
#include <hip/hip_runtime.h>

// ScRRAMBLe capsule layer — R11: transform rebuilt for TLP (the real hog).
//   A) xr[ch,c,k,m] = sum_{ij in ch} Ci[ij,c,k] * x[ij,m]   (R1 structure)
//   B) y[c,j,l]     = sum_{k,m} Wi[c,j,k,l,m] * xr[c,k,m]
//
// Unified fit across R1-R10 (overhead 143.8+-0.7): every round closes with
// TRANSFORM ~= 73us (Wi @ 1.8TB/s) regardless of variant; route was 4-30.
// 1.8TB/s => ~0.7MB chip outstanding vs 2.4MB BW-delay product. Old session
// VGPR=36: compiler keeps ~4 loads in flight/wave + vmcnt(0) drains; at 16
// waves/CU aggregate outstanding never saturates HBM. Fix: MORE WAVES with
// modest depth — explicit 8-deep batches (~58 VGPR peak), lb(256,6) ->
// 24 waves/CU x ~7KB avg outstanding ~= 170KB/CU >> 9.2KB needed.
// NCH 8->4 so the xr gather fits the register budget.
// Predicted: transform 73 -> 23-27us, route ~6, total ~176-185us.

typedef float f4 __attribute__((ext_vector_type(4)));

#define NCH 4   // ij chunks; xr partials = NCH*512*256 floats = 2 MB in d_ws

// ---------------- Kernel A: routing einsum (R1 lineage, NCH=4) -------------
// grid (128 i-quads, NCH); block 256.
// thread t: il = t>>6 (i within quad), g = (t>>4)&3 (ij subgroup), mq4 = t&15.
__global__ __launch_bounds__(256) void route_kernel(
    const float* __restrict__ x,
    const float* __restrict__ Ci,
    float* __restrict__ xr_part)
{
    const int iq  = blockIdx.x;
    const int c   = blockIdx.y;
    const int t   = threadIdx.x;
    const int il  = t >> 6;
    const int g   = (t >> 4) & 3;
    const int mq4 = t & 15;
    const int i   = (iq << 2) + il;

    const f4* __restrict__ Ci4 = (const f4*)Ci;
    const f4* __restrict__ x4  = (const f4*)x;

    __shared__ f4 part[1024];   // [g][il][r][mq4]

    f4 a0 = {0.f,0.f,0.f,0.f};
    f4 a1 = {0.f,0.f,0.f,0.f};
    f4 a2 = {0.f,0.f,0.f,0.f};
    f4 a3 = {0.f,0.f,0.f,0.f};

    const int ijpc = 2048 / NCH;      // 512
    const int sub  = ijpc >> 2;       // 128 per g-subgroup
    const int base = c * ijpc + g * sub;
    #pragma unroll 4
    for (int it = 0; it < sub; ++it) {
        const int ij = base + it;
        const f4 c4 = Ci4[ij * 512 + i];      // 4 uniq 16B gathers/wave (L3)
        const f4 xv = x4[(ij << 4) + mq4];    // 256B coalesced per g-group
        a0 += c4.x * xv;
        a1 += c4.y * xv;
        a2 += c4.z * xv;
        a3 += c4.w * xv;
    }

    const int pb = ((g << 2) + il) << 2;
    part[(pb + 0) * 16 + mq4] = a0;
    part[(pb + 1) * 16 + mq4] = a1;
    part[(pb + 2) * 16 + mq4] = a2;
    part[(pb + 3) * 16 + mq4] = a3;
    __syncthreads();

    // reduce over g: thread t owns (il2 = t>>6, r = (t>>4)&3, mm = t&15)
    const int il2 = t >> 6;
    const int r   = (t >> 4) & 3;
    const int mm  = t & 15;
    f4 s = {0.f,0.f,0.f,0.f};
    #pragma unroll
    for (int gg = 0; gg < 4; ++gg)
        s += part[(((gg << 2) + il2) * 4 + r) * 16 + mm];

    f4* __restrict__ xp4 = (f4*)xr_part;
    xp4[(c * 512 + (iq << 2) + il2) * 64 + r * 16 + mm] = s;
}

// ---------------- Kernel B: per-capsule transform, TLP-first ---------------
// grid 2048 = (i*4+j); block 256; wave w owns l in [w*16, w*16+16).
// Explicit 8-deep load batches, ~58 VGPR peak, lb(256,6) -> 24 waves/CU.
__global__ __launch_bounds__(256, 6) void transform_kernel(
    const float* __restrict__ Wi,
    const float* __restrict__ xr_part,
    float* __restrict__ y)
{
    const int b    = blockIdx.x;
    const int i    = b >> 2;
    const int t    = threadIdx.x;
    const int lane = t & 63;
    const int w    = t >> 6;
    const int lq   = lane >> 4;
    const int m16  = lane & 15;

    const f4* __restrict__ W4  = (const f4*)Wi;
    const f4* __restrict__ xp4 = (const f4*)xr_part;
    const int wbase = b << 12;          // b * 4096 f4
    const int lw    = w << 4;

    // xr gather: NCH=4 -> 16 loads in two 8-deep batches (8 transient regs).
    f4 xr0, xr1, xr2, xr3;
    {
        f4 tmp[8];
        #pragma unroll
        for (int ch = 0; ch < 2; ++ch)
            #pragma unroll
            for (int k = 0; k < 4; ++k)
                tmp[(ch << 2) + k] =
                    xp4[(((ch << 9) + i) << 6) + (k << 4) + m16];
        xr0 = tmp[0] + tmp[4];
        xr1 = tmp[1] + tmp[5];
        xr2 = tmp[2] + tmp[6];
        xr3 = tmp[3] + tmp[7];
        #pragma unroll
        for (int ch = 0; ch < 2; ++ch)
            #pragma unroll
            for (int k = 0; k < 4; ++k)
                tmp[(ch << 2) + k] =
                    xp4[((((ch + 2) << 9) + i) << 6) + (k << 4) + m16];
        xr0 += tmp[0] + tmp[4];
        xr1 += tmp[1] + tmp[5];
        xr2 += tmp[2] + tmp[6];
        xr3 += tmp[3] + tmp[7];
    }

    // Wi stream: 16 f4 loads as two 8-deep batches (registers reused).
    // Each load: 16 lanes x 16B contiguous x 4 lq rows = 1KB/wave-instr.
    #pragma unroll
    for (int half = 0; half < 2; ++half) {
        f4 wv[8];
        #pragma unroll
        for (int gsub = 0; gsub < 2; ++gsub) {
            const int c2 = (half << 1) + gsub;
            const int l  = lw + (c2 << 2) + lq;
            #pragma unroll
            for (int k = 0; k < 4; ++k)
                wv[(gsub << 2) + k] = __builtin_nontemporal_load(
                    &W4[wbase + (k << 10) + l * 16 + m16]);
        }
        #pragma unroll
        for (int gsub = 0; gsub < 2; ++gsub) {
            const int c2 = (half << 1) + gsub;
            const int l  = lw + (c2 << 2) + lq;
            f4 s = wv[(gsub << 2) + 0] * xr0
                 + wv[(gsub << 2) + 1] * xr1
                 + wv[(gsub << 2) + 2] * xr2
                 + wv[(gsub << 2) + 3] * xr3;
            float p = s.x + s.y + s.z + s.w;
            p += __shfl_xor(p, 1);
            p += __shfl_xor(p, 2);
            p += __shfl_xor(p, 4);
            p += __shfl_xor(p, 8);
            if (m16 == 0) y[(b << 6) + l] = p;
        }
    }
}

extern "C" void kernel_launch(void* const* d_in, const int* in_sizes, int n_in,
                              void* d_out, int out_size, void* d_ws, size_t ws_size,
                              hipStream_t stream) {
    const float* x  = (const float*)d_in[0];   // 131072 floats
    const float* Ci = (const float*)d_in[1];   // 2048*512*4 floats (16 MB)
    const float* Wi = (const float*)d_in[2];   // 512*4*4*64*64 floats (134 MB)
    float* y  = (float*)d_out;                 // 512*4*64 floats
    float* xr = (float*)d_ws;                  // 2 MB partials

    route_kernel<<<dim3(128, NCH), 256, 0, stream>>>(x, Ci, xr);
    transform_kernel<<<2048, 256, 0, stream>>>(Wi, xr, y);
}